// Round 5
// baseline (900.964 us; speedup 1.0000x reference)
//
#include <hip/hip_runtime.h>
#include <math.h>

#define B_   2
#define L_   1024
#define H_   8
#define DH_  128
#define NH_  2
#define HID_ 2048
#define T_   (L_ * NH_)    // 2048
#define KEY_ (H_ * DH_)    // 1024

typedef __attribute__((ext_vector_type(8))) short short8;
typedef __attribute__((ext_vector_type(4))) float f32x4;
typedef __attribute__((ext_vector_type(2))) float f32x2;

__device__ __forceinline__ ushort f2bf(float f) {
  unsigned u = __float_as_uint(f);
  u += 0x7fffu + ((u >> 16) & 1u);
  return (ushort)(u >> 16);
}

// ---------------- f32 -> bf16 conversion (vectorized) ----------------
__global__ __launch_bounds__(256) void cvt_bf16(const float* __restrict__ in,
                                                ushort* __restrict__ out, int n4) {
  int i = blockIdx.x * 256 + threadIdx.x;
  if (i >= n4) return;
  float4 v = ((const float4*)in)[i];
  ushort4 o;
  o.x = f2bf(v.x); o.y = f2bf(v.y); o.z = f2bf(v.z); o.w = f2bf(v.w);
  ((ushort4*)out)[i] = o;
}

// ---------------- bf16 MFMA GEMM (NT): C[M,N] = A[M,K] * W[N,K]^T ----------------
__device__ __forceinline__ void gload16(const void* g, void* l) {
  __builtin_amdgcn_global_load_lds(
      (const __attribute__((address_space(1))) unsigned*)g,
      (__attribute__((address_space(3))) unsigned*)l, 16, 0, 0);
}

__global__ __launch_bounds__(256) void gemm_bf16(
    const ushort* __restrict__ A, const ushort* __restrict__ W,
    float* __restrict__ C, int M, int N, int K) {
  __shared__ __align__(16) ushort As[128 * 32];
  __shared__ __align__(16) ushort Bs[128 * 32];
  const int tid = threadIdx.x;
  const int lane = tid & 63, wid = tid >> 6;
  const int wr = wid >> 1, wc = wid & 1;
  const int bm = blockIdx.y * 128, bn = blockIdx.x * 128;
  const int srow = tid >> 2, sch = (tid & 3) * 8;
  const ushort* ga = A + (size_t)(bm + srow) * K + sch;
  const ushort* gb = W + (size_t)(bn + srow) * K + sch;
  ushort* la = As + tid * 8;
  ushort* lb = Bs + tid * 8;
  const int frow = lane & 15;
  const int fk = (lane >> 4) * 8;
  f32x4 acc[4][4];
#pragma unroll
  for (int i = 0; i < 4; ++i)
#pragma unroll
    for (int j = 0; j < 4; ++j) acc[i][j] = (f32x4){0.f, 0.f, 0.f, 0.f};

  for (int k0 = 0; k0 < K; k0 += 32) {
    gload16(ga + k0, la);
    gload16(ga + k0 + (size_t)64 * K, la + 64 * 32);
    gload16(gb + k0, lb);
    gload16(gb + k0 + (size_t)64 * K, lb + 64 * 32);
    __syncthreads();
    short8 a[4], b[4];
#pragma unroll
    for (int m = 0; m < 4; ++m)
      a[m] = *(const short8*)(As + (wr * 64 + m * 16 + frow) * 32 + fk);
#pragma unroll
    for (int n = 0; n < 4; ++n)
      b[n] = *(const short8*)(Bs + (wc * 64 + n * 16 + frow) * 32 + fk);
#pragma unroll
    for (int m = 0; m < 4; ++m)
#pragma unroll
      for (int n = 0; n < 4; ++n)
        acc[m][n] = __builtin_amdgcn_mfma_f32_16x16x32_bf16(a[m], b[n], acc[m][n], 0, 0, 0);
    __syncthreads();
  }
  const int crow0 = (lane >> 4) * 4, ccol = lane & 15;
#pragma unroll
  for (int m = 0; m < 4; ++m)
#pragma unroll
    for (int n = 0; n < 4; ++n) {
      float* cp = C + (size_t)(bm + wr * 64 + m * 16 + crow0) * N + bn + wc * 64 + n * 16 + ccol;
#pragma unroll
      for (int j = 0; j < 4; ++j) cp[(size_t)j * N] = acc[m][n][j];
    }
}

// ------- small-N GEMM with fused nonlinearity epilogue -------
// MODE 0: identity   MODE 1: 2*sigmoid(s)   MODE 2: exp(-exp(A_log[n])*softplus(s+dt_bias[n]))
template <int MODE>
__global__ __launch_bounds__(256) void gemm_small(
    const float* __restrict__ X, const float* __restrict__ W,
    float* __restrict__ C, int M, int N, int K,
    const float* __restrict__ A_log, const float* __restrict__ dt_bias) {
  const int wid = blockIdx.x * 4 + (threadIdx.x >> 6);
  const int lane = threadIdx.x & 63;
  const int m = wid / N, n = wid - m * N;
  const float* xr = X + (size_t)m * K;
  const float* wr = W + (size_t)n * K;
  float s = 0.f;
  for (int k = lane * 4; k < K; k += 256) {
    const float4 a = *(const float4*)(xr + k);
    const float4 b = *(const float4*)(wr + k);
    s = fmaf(a.x, b.x, s); s = fmaf(a.y, b.y, s);
    s = fmaf(a.z, b.z, s); s = fmaf(a.w, b.w, s);
  }
#pragma unroll
  for (int mm = 32; mm; mm >>= 1) s += __shfl_xor(s, mm);
  if (lane == 0) {
    float r;
    if (MODE == 1) {
      r = 2.f / (1.f + expf(-s));
    } else if (MODE == 2) {
      const float xs = s + dt_bias[n];
      const float sp = (xs > 20.f) ? xs : log1pf(expf(xs));
      r = expf(-expf(A_log[n]) * sp);
    } else {
      r = s;
    }
    C[(size_t)m * N + n] = r;
  }
}

// ------------- causal depthwise conv(K=4) + SiLU (+ optional L2 norm) -------------
template <int NORM>
__global__ __launch_bounds__(128) void conv_silu_norm(
    const float* __restrict__ in, const float* __restrict__ cw,
    float* __restrict__ out, int C, float scale) {
  const int bl = blockIdx.x;            // b*L + l
  const int l = bl & (L_ - 1);
  const int c = blockIdx.y * 128 + threadIdx.x;
  const size_t base = (size_t)bl * C + c;
  const float w0 = cw[c * 4 + 0], w1 = cw[c * 4 + 1];
  const float w2 = cw[c * 4 + 2], w3 = cw[c * 4 + 3];
  float acc = w3 * in[base];
  if (l >= 1) acc = fmaf(w2, in[base - (size_t)C], acc);
  if (l >= 2) acc = fmaf(w1, in[base - 2 * (size_t)C], acc);
  if (l >= 3) acc = fmaf(w0, in[base - 3 * (size_t)C], acc);
  float y = acc / (1.f + expf(-acc));   // silu
  if (NORM) {
    float ss = y * y;
#pragma unroll
    for (int mm = 32; mm; mm >>= 1) ss += __shfl_xor(ss, mm);
    __shared__ float p[2];
    if ((threadIdx.x & 63) == 0) p[threadIdx.x >> 6] = ss;
    __syncthreads();
    const float tot = p[0] + p[1];
    y *= scale / fmaxf(sqrtf(tot), 1e-12f);
  }
  out[base] = y;
}

// ------- per-token scalar pack: {decay, b0, b1, k1.k0, q.k0, q.k1, 0, 0} -------
__global__ __launch_bounds__(256) void dots_kernel(
    const float* __restrict__ kn, const float* __restrict__ qn,
    const float* __restrict__ dka, const float* __restrict__ ba,
    float* __restrict__ sc) {
  const int idx = blockIdx.x * 4 + (threadIdx.x >> 6);   // (b*L+l)*H + h
  const int lane = threadIdx.x & 63;
  const int h = idx & 7;
  const int bl = idx >> 3;            // b*L + l
  const int l = bl & (L_ - 1);
  const int b = bl >> 10;
  const float* k0 = kn + ((size_t)b * T_ + 2 * l) * 1024 + h * 128;
  const float* k1 = k0 + 1024;
  const float* q  = qn + (size_t)bl * 1024 + h * 128;
  const f32x2 k0v = *(const f32x2*)(k0 + lane * 2);
  const f32x2 k1v = *(const f32x2*)(k1 + lane * 2);
  const f32x2 qv  = *(const f32x2*)(q + lane * 2);
  const f32x2 p00 = k1v * k0v, pq0 = qv * k0v, pq1 = qv * k1v;
  float d00 = p00.x + p00.y, dq0 = pq0.x + pq0.y, dq1 = pq1.x + pq1.y;
#pragma unroll
  for (int mm = 32; mm; mm >>= 1) {
    d00 += __shfl_xor(d00, mm);
    dq0 += __shfl_xor(dq0, mm);
    dq1 += __shfl_xor(dq1, mm);
  }
  if (lane == 0) {
    float4* dst = (float4*)(sc + (size_t)idx * 8);
    dst[0] = (float4){dka[bl * 8 + h], ba[bl * 16 + h], ba[bl * 16 + 8 + h], d00};
    dst[1] = (float4){dq0, dq1, 0.f, 0.f};
  }
}

// ---------------- sequential gated delta-product scan ----------------
// lane = vl*16 + kg (kg = lane&15, vl = lane>>4): column v = vb*4+vl,
// k-rows kg*8 .. kg*8+7 (8 cells as 4 f32x2). k-reduction over the low
// 4 lane bits -> pure-VALU DPP (xor1, xor2, half_mirror, row_mirror).

__device__ __forceinline__ float dpp_red16(float x) {
  int t;
  t = __builtin_amdgcn_mov_dpp(__float_as_int(x), 0xB1, 0xf, 0xf, true);   // quad_perm [1,0,3,2]
  x += __int_as_float(t);
  t = __builtin_amdgcn_mov_dpp(__float_as_int(x), 0x4E, 0xf, 0xf, true);   // quad_perm [2,3,0,1]
  x += __int_as_float(t);
  t = __builtin_amdgcn_mov_dpp(__float_as_int(x), 0x141, 0xf, 0xf, true);  // row_half_mirror
  x += __int_as_float(t);
  t = __builtin_amdgcn_mov_dpp(__float_as_int(x), 0x140, 0xf, 0xf, true);  // row_mirror
  x += __int_as_float(t);
  return x;
}

union V8 {
  float4 v4[2];
  f32x2  v2[4];
};

struct Tok {
  V8 k0, k1, q;
  float4 s0, s1;       // {dk,b0,b1,d00}, {dq0,dq1,_,_}
  float v0, v1;
};

__device__ __forceinline__ void load_tok(Tok& t, int l,
    const float* __restrict__ kp, const float* __restrict__ vp,
    const float* __restrict__ qp, const float* __restrict__ scp) {
  const float* kpt = kp + (size_t)(2 * l) * 1024;
  t.k0.v4[0] = *(const float4*)(kpt);
  t.k0.v4[1] = *(const float4*)(kpt + 4);
  t.k1.v4[0] = *(const float4*)(kpt + 1024);
  t.k1.v4[1] = *(const float4*)(kpt + 1028);
  const float* qpt = qp + (size_t)l * 1024;
  t.q.v4[0] = *(const float4*)(qpt);
  t.q.v4[1] = *(const float4*)(qpt + 4);
  const float* scl = scp + (size_t)l * 64;
  t.s0 = *(const float4*)(scl);
  t.s1 = *(const float4*)(scl + 4);
  t.v0 = vp[(size_t)(2 * l) * 1024];
  t.v1 = vp[(size_t)(2 * l) * 1024 + 1024];
}

__device__ __forceinline__ void proc_tok(const Tok& t, int l,
                                         f32x2 st[4], int lane, float* __restrict__ op) {
  // three concurrent reductions on the PRE-update state S0
  f32x2 a0, a1, b0v, b1v, c0v, c1v;
  a0  = t.k0.v2[0] * st[0]; a0  = __builtin_elementwise_fma(t.k0.v2[2], st[2], a0);
  a1  = t.k0.v2[1] * st[1]; a1  = __builtin_elementwise_fma(t.k0.v2[3], st[3], a1);
  b0v = t.k1.v2[0] * st[0]; b0v = __builtin_elementwise_fma(t.k1.v2[2], st[2], b0v);
  b1v = t.k1.v2[1] * st[1]; b1v = __builtin_elementwise_fma(t.k1.v2[3], st[3], b1v);
  c0v = t.q.v2[0]  * st[0]; c0v = __builtin_elementwise_fma(t.q.v2[2],  st[2], c0v);
  c1v = t.q.v2[1]  * st[1]; c1v = __builtin_elementwise_fma(t.q.v2[3],  st[3], c1v);
  const f32x2 sa = a0 + a1, sb = b0v + b1v, sq = c0v + c1v;
  const float c0 = dpp_red16(sa.x + sa.y);
  const float c1 = dpp_red16(sb.x + sb.y);
  const float cq = dpp_red16(sq.x + sq.y);
  // scalar combine
  const float g = t.s0.x, bb0 = t.s0.y, bb1 = t.s0.z, d00 = t.s0.w;
  const float dq0 = t.s1.x, dq1 = t.s1.y;
  const float vn0 = (t.v0 - g * c0) * bb0;
  const float vn1 = (t.v1 - fmaf(d00, vn0, g * c1)) * bb1;
  const float osum = fmaf(dq1, vn1, fmaf(dq0, vn0, g * cq));
  // fused state update: S = g*S + k0*vn0 + k1*vn1
  const f32x2 g2 = {g, g}, w0 = {vn0, vn0}, w1 = {vn1, vn1};
#pragma unroll
  for (int p = 0; p < 4; ++p) {
    f32x2 s = st[p] * g2;
    s = __builtin_elementwise_fma(t.k0.v2[p], w0, s);
    st[p] = __builtin_elementwise_fma(t.k1.v2[p], w1, s);
  }
  if ((lane & 15) == 0) op[(size_t)l * 1024] = osum;
}

__global__ __launch_bounds__(64, 1) void scan_kernel(
    const float* __restrict__ qn, const float* __restrict__ kn,
    const float* __restrict__ vc, const float* __restrict__ sc,
    float* __restrict__ o, float* __restrict__ fstate) {
  // XCD-aware remap: all 32 vb-blocks of one (b,h) group land on ONE XCD.
  const int bid = blockIdx.x;          // 512 blocks
  const int xcd = bid & 7;
  const int rest = bid >> 3;           // 0..63
  const int vb = rest & 31;
  const int g = ((rest >> 5) << 3) + xcd;   // (b,h) group id, 0..15
  const int h = g & 7;
  const int b = g >> 3;
  const int lane = threadIdx.x;
  const int kg = lane & 15, vl = lane >> 4;
  const int v = vb * 4 + vl;
  const float* kp = kn + (size_t)b * T_ * 1024 + h * 128 + kg * 8;
  const float* vp = vc + (size_t)b * T_ * 1024 + h * 128 + v;
  const float* qp = qn + (size_t)b * L_ * 1024 + h * 128 + kg * 8;
  const float* scp = sc + ((size_t)b * L_ * 8 + h) * 8;
  float* op = o + (size_t)b * L_ * 1024 + h * 128 + v;

  f32x2 st[4];
#pragma unroll
  for (int j = 0; j < 4; ++j) st[j] = (f32x2){0.f, 0.f};

  Tok t0, t1, t2, t3;
  load_tok(t0, 0, kp, vp, qp, scp);
  load_tok(t1, 1, kp, vp, qp, scp);
  load_tok(t2, 2, kp, vp, qp, scp);
  load_tok(t3, 3, kp, vp, qp, scp);
  for (int l = 0; l < L_; l += 4) {
    proc_tok(t0, l, st, lane, op);
    if (l + 4 < L_) load_tok(t0, l + 4, kp, vp, qp, scp);
    proc_tok(t1, l + 1, st, lane, op);
    if (l + 5 < L_) load_tok(t1, l + 5, kp, vp, qp, scp);
    proc_tok(t2, l + 2, st, lane, op);
    if (l + 6 < L_) load_tok(t2, l + 6, kp, vp, qp, scp);
    proc_tok(t3, l + 3, st, lane, op);
    if (l + 7 < L_) load_tok(t3, l + 7, kp, vp, qp, scp);
  }
  float* fp = fstate + (size_t)(b * H_ + h) * (128 * 128) + (size_t)(kg * 8) * 128 + v;
#pragma unroll
  for (int p = 0; p < 4; ++p) {
    fp[(size_t)(2 * p) * 128] = st[p].x;
    fp[(size_t)(2 * p + 1) * 128] = st[p].y;
  }
}

// ---------------- gated RMSNorm: on = rms(o)*w*silu(gg), bf16 out ----------------
__global__ __launch_bounds__(128) void rmsnorm_gate(
    const float* __restrict__ o, const float* __restrict__ gg,
    const float* __restrict__ w, ushort* __restrict__ on) {
  const int blk = blockIdx.x;       // (b*L+l)*H + h
  const int d = threadIdx.x;
  const size_t base = (size_t)blk * 128 + d;
  const float x = o[base];
  float ss = x * x;
#pragma unroll
  for (int mm = 32; mm; mm >>= 1) ss += __shfl_xor(ss, mm);
  __shared__ float p[2];
  if ((d & 63) == 0) p[d >> 6] = ss;
  __syncthreads();
  const float tot = p[0] + p[1];
  const float r = rsqrtf(tot * (1.f / 128.f) + 1e-5f);
  const float gv = gg[base];
  on[base] = f2bf(x * r * w[d] * (gv / (1.f + expf(-gv))));
}

extern "C" void kernel_launch(void* const* d_in, const int* in_sizes, int n_in,
                              void* d_out, int out_size, void* d_ws, size_t ws_size,
                              hipStream_t stream) {
  const float* x       = (const float*)d_in[0];
  const float* Wq      = (const float*)d_in[1];
  const float* Wk      = (const float*)d_in[2];
  const float* Wv      = (const float*)d_in[3];
  const float* Wb      = (const float*)d_in[4];
  const float* Wa      = (const float*)d_in[5];
  const float* Wg      = (const float*)d_in[6];
  const float* Wo      = (const float*)d_in[7];
  const float* A_log   = (const float*)d_in[8];
  const float* dt_bias = (const float*)d_in[9];
  const float* conv_q  = (const float*)d_in[10];
  const float* conv_k  = (const float*)d_in[11];
  const float* conv_v  = (const float*)d_in[12];
  const float* o_norm_w= (const float*)d_in[13];

  float* ws = (float*)d_ws;
  float* pa = ws;                   // 4,194,304 f32 (proj scratch; later scan output)
  float* kn = pa + 4194304;         // 4,194,304 f32
  float* vc = kn + 4194304;         // 4,194,304 f32
  float* qn = vc + 4194304;         // 2,097,152 f32
  float* gg = qn + 2097152;         // 2,097,152 f32
  float* ba = gg + 2097152;         // 32,768 f32  (pre-transformed: 2*sigmoid)
  float* dka = ba + 32768;          // 16,384 f32  (pre-transformed: decay)
  ushort* xb  = (ushort*)(dka + 16384);       // 4,194,304 bf16
  ushort* wb  = xb + 4194304;                 // 4,194,304 bf16
  ushort* pab = wb + 4194304;                 // 2,097,152 bf16
  float* sc = (float*)(pab + 2097152);        // 131,072 f32 per-token scalar packs

  float* out = (float*)d_out;
  float* fstate = out + (size_t)B_ * L_ * HID_;

  const int M = B_ * L_;            // 2048

  // x -> bf16 once
  cvt_bf16<<<4096, 256, 0, stream>>>(x, xb, 1048576);
  // k: proj -> conv+silu+l2norm
  cvt_bf16<<<4096, 256, 0, stream>>>(Wk, wb, 1048576);
  gemm_bf16<<<dim3(16, 16), 256, 0, stream>>>(xb, wb, pa, M, 2048, HID_);
  conv_silu_norm<1><<<dim3(M, 16), 128, 0, stream>>>(pa, conv_k, kn, 2048, 1.0f);
  // v: proj -> conv+silu
  cvt_bf16<<<4096, 256, 0, stream>>>(Wv, wb, 1048576);
  gemm_bf16<<<dim3(16, 16), 256, 0, stream>>>(xb, wb, pa, M, 2048, HID_);
  conv_silu_norm<0><<<dim3(M, 16), 128, 0, stream>>>(pa, conv_v, vc, 2048, 1.0f);
  // q: proj -> conv+silu+l2norm, scaled by 1/sqrt(DH)
  cvt_bf16<<<2048, 256, 0, stream>>>(Wq, wb, 524288);
  gemm_bf16<<<dim3(8, 16), 256, 0, stream>>>(xb, wb, pa, M, KEY_, HID_);
  conv_silu_norm<1><<<dim3(M, 8), 128, 0, stream>>>(pa, conv_q, qn, KEY_,
                                                    0.08838834764831845f);
  // gate projection
  cvt_bf16<<<2048, 256, 0, stream>>>(Wg, wb, 524288);
  gemm_bf16<<<dim3(8, 16), 256, 0, stream>>>(xb, wb, gg, M, KEY_, HID_);
  // beta / decay projections with fused nonlinearity
  gemm_small<1><<<dim3(M * 16 / 4), 256, 0, stream>>>(x, Wb, ba, M, 16, HID_, nullptr, nullptr);
  gemm_small<2><<<dim3(M * 8 / 4), 256, 0, stream>>>(x, Wa, dka, M, 8, HID_, A_log, dt_bias);
  // per-token scalar precompute (k1.k0, q.k0, q.k1 + gather dk/b0/b1)
  dots_kernel<<<dim3(M * H_ / 4), 256, 0, stream>>>(kn, qn, dka, ba, sc);
  // sequential scan (512 independent single-wave blocks, XCD-grouped, DPP reductions)
  scan_kernel<<<dim3(B_ * H_ * 32), 64, 0, stream>>>(qn, kn, vc, sc, pa, fstate);
  // epilogue: gated RMSNorm (bf16 out) then output projection
  rmsnorm_gate<<<dim3(M * H_), 128, 0, stream>>>(pa, gg, o_norm_w, pab);
  cvt_bf16<<<2048, 256, 0, stream>>>(Wo, wb, 524288);
  gemm_bf16<<<dim3(16, 16), 256, 0, stream>>>(pab, wb, out, M, HID_, KEY_);
}

// Round 9
// 866.405 us; speedup vs baseline: 1.0399x; 1.0399x over previous
//
#include <hip/hip_runtime.h>
#include <math.h>

#define B_   2
#define L_   1024
#define H_   8
#define DH_  128
#define NH_  2
#define HID_ 2048
#define T_   (L_ * NH_)    // 2048
#define KEY_ (H_ * DH_)    // 1024

typedef __attribute__((ext_vector_type(8))) short short8;
typedef __attribute__((ext_vector_type(4))) float f32x4;
typedef __attribute__((ext_vector_type(2))) float f32x2;

__device__ __forceinline__ ushort f2bf(float f) {
  unsigned u = __float_as_uint(f);
  u += 0x7fffu + ((u >> 16) & 1u);
  return (ushort)(u >> 16);
}

// ---------------- f32 -> bf16 conversion (vectorized) ----------------
__global__ __launch_bounds__(256) void cvt_bf16(const float* __restrict__ in,
                                                ushort* __restrict__ out, int n4) {
  int i = blockIdx.x * 256 + threadIdx.x;
  if (i >= n4) return;
  float4 v = ((const float4*)in)[i];
  ushort4 o;
  o.x = f2bf(v.x); o.y = f2bf(v.y); o.z = f2bf(v.z); o.w = f2bf(v.w);
  ((ushort4*)out)[i] = o;
}

// ---------------- bf16 MFMA GEMM (NT): C[M,N] = A[M,K] * W[N,K]^T ----------------
__device__ __forceinline__ void gload16(const void* g, void* l) {
  __builtin_amdgcn_global_load_lds(
      (const __attribute__((address_space(1))) unsigned*)g,
      (__attribute__((address_space(3))) unsigned*)l, 16, 0, 0);
}

__global__ __launch_bounds__(256) void gemm_bf16(
    const ushort* __restrict__ A, const ushort* __restrict__ W,
    float* __restrict__ C, int M, int N, int K) {
  __shared__ __align__(16) ushort As[128 * 32];
  __shared__ __align__(16) ushort Bs[128 * 32];
  const int tid = threadIdx.x;
  const int lane = tid & 63, wid = tid >> 6;
  const int wr = wid >> 1, wc = wid & 1;
  const int bm = blockIdx.y * 128, bn = blockIdx.x * 128;
  const int srow = tid >> 2, sch = (tid & 3) * 8;
  const ushort* ga = A + (size_t)(bm + srow) * K + sch;
  const ushort* gb = W + (size_t)(bn + srow) * K + sch;
  ushort* la = As + tid * 8;
  ushort* lb = Bs + tid * 8;
  const int frow = lane & 15;
  const int fk = (lane >> 4) * 8;
  f32x4 acc[4][4];
#pragma unroll
  for (int i = 0; i < 4; ++i)
#pragma unroll
    for (int j = 0; j < 4; ++j) acc[i][j] = (f32x4){0.f, 0.f, 0.f, 0.f};

  for (int k0 = 0; k0 < K; k0 += 32) {
    gload16(ga + k0, la);
    gload16(ga + k0 + (size_t)64 * K, la + 64 * 32);
    gload16(gb + k0, lb);
    gload16(gb + k0 + (size_t)64 * K, lb + 64 * 32);
    __syncthreads();
    short8 a[4], b[4];
#pragma unroll
    for (int m = 0; m < 4; ++m)
      a[m] = *(const short8*)(As + (wr * 64 + m * 16 + frow) * 32 + fk);
#pragma unroll
    for (int n = 0; n < 4; ++n)
      b[n] = *(const short8*)(Bs + (wc * 64 + n * 16 + frow) * 32 + fk);
#pragma unroll
    for (int m = 0; m < 4; ++m)
#pragma unroll
      for (int n = 0; n < 4; ++n)
        acc[m][n] = __builtin_amdgcn_mfma_f32_16x16x32_bf16(a[m], b[n], acc[m][n], 0, 0, 0);
    __syncthreads();
  }
  const int crow0 = (lane >> 4) * 4, ccol = lane & 15;
#pragma unroll
  for (int m = 0; m < 4; ++m)
#pragma unroll
    for (int n = 0; n < 4; ++n) {
      float* cp = C + (size_t)(bm + wr * 64 + m * 16 + crow0) * N + bn + wc * 64 + n * 16 + ccol;
#pragma unroll
      for (int j = 0; j < 4; ++j) cp[(size_t)j * N] = acc[m][n][j];
    }
}

// ------- small-N GEMM with fused nonlinearity epilogue -------
// MODE 0: identity   MODE 1: 2*sigmoid(s)   MODE 2: exp(-exp(A_log[n])*softplus(s+dt_bias[n]))
template <int MODE>
__global__ __launch_bounds__(256) void gemm_small(
    const float* __restrict__ X, const float* __restrict__ W,
    float* __restrict__ C, int M, int N, int K,
    const float* __restrict__ A_log, const float* __restrict__ dt_bias) {
  const int wid = blockIdx.x * 4 + (threadIdx.x >> 6);
  const int lane = threadIdx.x & 63;
  const int m = wid / N, n = wid - m * N;
  const float* xr = X + (size_t)m * K;
  const float* wr = W + (size_t)n * K;
  float s = 0.f;
  for (int k = lane * 4; k < K; k += 256) {
    const float4 a = *(const float4*)(xr + k);
    const float4 b = *(const float4*)(wr + k);
    s = fmaf(a.x, b.x, s); s = fmaf(a.y, b.y, s);
    s = fmaf(a.z, b.z, s); s = fmaf(a.w, b.w, s);
  }
#pragma unroll
  for (int mm = 32; mm; mm >>= 1) s += __shfl_xor(s, mm);
  if (lane == 0) {
    float r;
    if (MODE == 1) {
      r = 2.f / (1.f + expf(-s));
    } else if (MODE == 2) {
      const float xs = s + dt_bias[n];
      const float sp = (xs > 20.f) ? xs : log1pf(expf(xs));
      r = expf(-expf(A_log[n]) * sp);
    } else {
      r = s;
    }
    C[(size_t)m * N + n] = r;
  }
}

// ------------- causal depthwise conv(K=4) + SiLU (+ optional L2 norm) -------------
template <int NORM>
__global__ __launch_bounds__(128) void conv_silu_norm(
    const float* __restrict__ in, const float* __restrict__ cw,
    float* __restrict__ out, int C, float scale) {
  const int bl = blockIdx.x;            // b*L + l
  const int l = bl & (L_ - 1);
  const int c = blockIdx.y * 128 + threadIdx.x;
  const size_t base = (size_t)bl * C + c;
  const float w0 = cw[c * 4 + 0], w1 = cw[c * 4 + 1];
  const float w2 = cw[c * 4 + 2], w3 = cw[c * 4 + 3];
  float acc = w3 * in[base];
  if (l >= 1) acc = fmaf(w2, in[base - (size_t)C], acc);
  if (l >= 2) acc = fmaf(w1, in[base - 2 * (size_t)C], acc);
  if (l >= 3) acc = fmaf(w0, in[base - 3 * (size_t)C], acc);
  float y = acc / (1.f + expf(-acc));   // silu
  if (NORM) {
    float ss = y * y;
#pragma unroll
    for (int mm = 32; mm; mm >>= 1) ss += __shfl_xor(ss, mm);
    __shared__ float p[2];
    if ((threadIdx.x & 63) == 0) p[threadIdx.x >> 6] = ss;
    __syncthreads();
    const float tot = p[0] + p[1];
    y *= scale / fmaxf(sqrtf(tot), 1e-12f);
  }
  out[base] = y;
}

// ------- per-token scalar pack: {decay, b0, b1, k1.k0, q.k0, q.k1, 0, 0} -------
__global__ __launch_bounds__(256) void dots_kernel(
    const float* __restrict__ kn, const float* __restrict__ qn,
    const float* __restrict__ dka, const float* __restrict__ ba,
    float* __restrict__ sc) {
  const int idx = blockIdx.x * 4 + (threadIdx.x >> 6);   // (b*L+l)*H + h
  const int lane = threadIdx.x & 63;
  const int h = idx & 7;
  const int bl = idx >> 3;            // b*L + l
  const int l = bl & (L_ - 1);
  const int b = bl >> 10;
  const float* k0 = kn + ((size_t)b * T_ + 2 * l) * 1024 + h * 128;
  const float* k1 = k0 + 1024;
  const float* q  = qn + (size_t)bl * 1024 + h * 128;
  const f32x2 k0v = *(const f32x2*)(k0 + lane * 2);
  const f32x2 k1v = *(const f32x2*)(k1 + lane * 2);
  const f32x2 qv  = *(const f32x2*)(q + lane * 2);
  const f32x2 p00 = k1v * k0v, pq0 = qv * k0v, pq1 = qv * k1v;
  float d00 = p00.x + p00.y, dq0 = pq0.x + pq0.y, dq1 = pq1.x + pq1.y;
#pragma unroll
  for (int mm = 32; mm; mm >>= 1) {
    d00 += __shfl_xor(d00, mm);
    dq0 += __shfl_xor(dq0, mm);
    dq1 += __shfl_xor(dq1, mm);
  }
  if (lane == 0) {
    float4* dst = (float4*)(sc + (size_t)idx * 8);
    dst[0] = (float4){dka[bl * 8 + h], ba[bl * 16 + h], ba[bl * 16 + 8 + h], d00};
    dst[1] = (float4){dq0, dq1, 0.f, 0.f};
  }
}

// ---------------- sequential gated delta-product scan ----------------
// lane = vl*16 + kg (kg = lane&15, vl = lane>>4): column v = vb*4+vl,
// k-rows kg*8 .. kg*8+7 (8 cells as 4 f32x2). k-reduction over the low
// 4 lane bits -> pure-VALU DPP (xor1, xor2, half_mirror, row_mirror).

__device__ __forceinline__ float dpp_red16(float x) {
  int t;
  t = __builtin_amdgcn_mov_dpp(__float_as_int(x), 0xB1, 0xf, 0xf, true);   // quad_perm [1,0,3,2]
  x += __int_as_float(t);
  t = __builtin_amdgcn_mov_dpp(__float_as_int(x), 0x4E, 0xf, 0xf, true);   // quad_perm [2,3,0,1]
  x += __int_as_float(t);
  t = __builtin_amdgcn_mov_dpp(__float_as_int(x), 0x141, 0xf, 0xf, true);  // row_half_mirror
  x += __int_as_float(t);
  t = __builtin_amdgcn_mov_dpp(__float_as_int(x), 0x140, 0xf, 0xf, true);  // row_mirror
  x += __int_as_float(t);
  return x;
}

union V8 {
  float4 v4[2];
  f32x2  v2[4];
};

struct Tok {
  V8 k0, k1, q;
  float4 s0, s1;       // {dk,b0,b1,d00}, {dq0,dq1,_,_}
  float v0, v1;
};

__device__ __forceinline__ void load_tok(Tok& t, int l,
    const float* __restrict__ kp, const float* __restrict__ vp,
    const float* __restrict__ qp, const float* __restrict__ scp) {
  const float* kpt = kp + (size_t)(2 * l) * 1024;
  t.k0.v4[0] = *(const float4*)(kpt);
  t.k0.v4[1] = *(const float4*)(kpt + 4);
  t.k1.v4[0] = *(const float4*)(kpt + 1024);
  t.k1.v4[1] = *(const float4*)(kpt + 1028);
  const float* qpt = qp + (size_t)l * 1024;
  t.q.v4[0] = *(const float4*)(qpt);
  t.q.v4[1] = *(const float4*)(qpt + 4);
  const float* scl = scp + (size_t)l * 64;
  t.s0 = *(const float4*)(scl);
  t.s1 = *(const float4*)(scl + 4);
  t.v0 = vp[(size_t)(2 * l) * 1024];
  t.v1 = vp[(size_t)(2 * l) * 1024 + 1024];
}

__device__ __forceinline__ void proc_tok(const Tok& t, int l,
                                         f32x2 st[4], int lane, float* __restrict__ op) {
  // three concurrent reductions on the PRE-update state S0
  f32x2 a0, a1, b0v, b1v, c0v, c1v;
  a0  = t.k0.v2[0] * st[0]; a0  = __builtin_elementwise_fma(t.k0.v2[2], st[2], a0);
  a1  = t.k0.v2[1] * st[1]; a1  = __builtin_elementwise_fma(t.k0.v2[3], st[3], a1);
  b0v = t.k1.v2[0] * st[0]; b0v = __builtin_elementwise_fma(t.k1.v2[2], st[2], b0v);
  b1v = t.k1.v2[1] * st[1]; b1v = __builtin_elementwise_fma(t.k1.v2[3], st[3], b1v);
  c0v = t.q.v2[0]  * st[0]; c0v = __builtin_elementwise_fma(t.q.v2[2],  st[2], c0v);
  c1v = t.q.v2[1]  * st[1]; c1v = __builtin_elementwise_fma(t.q.v2[3],  st[3], c1v);
  const f32x2 sa = a0 + a1, sb = b0v + b1v, sq = c0v + c1v;
  const float c0 = dpp_red16(sa.x + sa.y);
  const float c1 = dpp_red16(sb.x + sb.y);
  const float cq = dpp_red16(sq.x + sq.y);
  // scalar combine
  const float g = t.s0.x, bb0 = t.s0.y, bb1 = t.s0.z, d00 = t.s0.w;
  const float dq0 = t.s1.x, dq1 = t.s1.y;
  const float vn0 = (t.v0 - g * c0) * bb0;
  const float vn1 = (t.v1 - fmaf(d00, vn0, g * c1)) * bb1;
  const float osum = fmaf(dq1, vn1, fmaf(dq0, vn0, g * cq));
  // fused state update: S = g*S + k0*vn0 + k1*vn1
  const f32x2 g2 = {g, g}, w0 = {vn0, vn0}, w1 = {vn1, vn1};
#pragma unroll
  for (int p = 0; p < 4; ++p) {
    f32x2 s = st[p] * g2;
    s = __builtin_elementwise_fma(t.k0.v2[p], w0, s);
    st[p] = __builtin_elementwise_fma(t.k1.v2[p], w1, s);
  }
  if ((lane & 15) == 0) op[(size_t)l * 1024] = osum;
}

__global__ __launch_bounds__(64, 1) void scan_kernel(
    const float* __restrict__ qn, const float* __restrict__ kn,
    const float* __restrict__ vc, const float* __restrict__ sc,
    float* __restrict__ o, float* __restrict__ fstate) {
  // XCD-aware remap: all 32 vb-blocks of one (b,h) group land on ONE XCD.
  const int bid = blockIdx.x;          // 512 blocks
  const int xcd = bid & 7;
  const int rest = bid >> 3;           // 0..63
  const int vb = rest & 31;
  const int g = ((rest >> 5) << 3) + xcd;   // (b,h) group id, 0..15
  const int h = g & 7;
  const int b = g >> 3;
  const int lane = threadIdx.x;
  const int kg = lane & 15, vl = lane >> 4;
  const int v = vb * 4 + vl;
  const float* kp = kn + (size_t)b * T_ * 1024 + h * 128 + kg * 8;
  const float* vp = vc + (size_t)b * T_ * 1024 + h * 128 + v;
  const float* qp = qn + (size_t)b * L_ * 1024 + h * 128 + kg * 8;
  const float* scp = sc + ((size_t)b * L_ * 8 + h) * 8;
  float* op = o + (size_t)b * L_ * 1024 + h * 128 + v;

  f32x2 st[4];
#pragma unroll
  for (int j = 0; j < 4; ++j) st[j] = (f32x2){0.f, 0.f};

  // depth-4 prefetch ring. sched_barrier(0) after each load_tok pins the
  // loads in program order (prevents the scheduler from sinking them to
  // just-before-use and collapsing the ring into one Tok's registers —
  // round-5 evidence: VGPR_Count=80 < 4 live Toks, VALUBusy 16%).
  Tok t0, t1, t2, t3;
  load_tok(t0, 0, kp, vp, qp, scp);
  __builtin_amdgcn_sched_barrier(0);
  load_tok(t1, 1, kp, vp, qp, scp);
  __builtin_amdgcn_sched_barrier(0);
  load_tok(t2, 2, kp, vp, qp, scp);
  __builtin_amdgcn_sched_barrier(0);
  load_tok(t3, 3, kp, vp, qp, scp);
  __builtin_amdgcn_sched_barrier(0);
  for (int l = 0; l < L_; l += 4) {
    proc_tok(t0, l, st, lane, op);
    if (l + 4 < L_) load_tok(t0, l + 4, kp, vp, qp, scp);
    __builtin_amdgcn_sched_barrier(0);
    proc_tok(t1, l + 1, st, lane, op);
    if (l + 5 < L_) load_tok(t1, l + 5, kp, vp, qp, scp);
    __builtin_amdgcn_sched_barrier(0);
    proc_tok(t2, l + 2, st, lane, op);
    if (l + 6 < L_) load_tok(t2, l + 6, kp, vp, qp, scp);
    __builtin_amdgcn_sched_barrier(0);
    proc_tok(t3, l + 3, st, lane, op);
    if (l + 7 < L_) load_tok(t3, l + 7, kp, vp, qp, scp);
    __builtin_amdgcn_sched_barrier(0);
  }
  float* fp = fstate + (size_t)(b * H_ + h) * (128 * 128) + (size_t)(kg * 8) * 128 + v;
#pragma unroll
  for (int p = 0; p < 4; ++p) {
    fp[(size_t)(2 * p) * 128] = st[p].x;
    fp[(size_t)(2 * p + 1) * 128] = st[p].y;
  }
}

// ---------------- gated RMSNorm: on = rms(o)*w*silu(gg), bf16 out ----------------
__global__ __launch_bounds__(128) void rmsnorm_gate(
    const float* __restrict__ o, const float* __restrict__ gg,
    const float* __restrict__ w, ushort* __restrict__ on) {
  const int blk = blockIdx.x;       // (b*L+l)*H + h
  const int d = threadIdx.x;
  const size_t base = (size_t)blk * 128 + d;
  const float x = o[base];
  float ss = x * x;
#pragma unroll
  for (int mm = 32; mm; mm >>= 1) ss += __shfl_xor(ss, mm);
  __shared__ float p[2];
  if ((d & 63) == 0) p[d >> 6] = ss;
  __syncthreads();
  const float tot = p[0] + p[1];
  const float r = rsqrtf(tot * (1.f / 128.f) + 1e-5f);
  const float gv = gg[base];
  on[base] = f2bf(x * r * w[d] * (gv / (1.f + expf(-gv))));
}

extern "C" void kernel_launch(void* const* d_in, const int* in_sizes, int n_in,
                              void* d_out, int out_size, void* d_ws, size_t ws_size,
                              hipStream_t stream) {
  const float* x       = (const float*)d_in[0];
  const float* Wq      = (const float*)d_in[1];
  const float* Wk      = (const float*)d_in[2];
  const float* Wv      = (const float*)d_in[3];
  const float* Wb      = (const float*)d_in[4];
  const float* Wa      = (const float*)d_in[5];
  const float* Wg      = (const float*)d_in[6];
  const float* Wo      = (const float*)d_in[7];
  const float* A_log   = (const float*)d_in[8];
  const float* dt_bias = (const float*)d_in[9];
  const float* conv_q  = (const float*)d_in[10];
  const float* conv_k  = (const float*)d_in[11];
  const float* conv_v  = (const float*)d_in[12];
  const float* o_norm_w= (const float*)d_in[13];

  float* ws = (float*)d_ws;
  float* pa = ws;                   // 4,194,304 f32 (proj scratch; later scan output)
  float* kn = pa + 4194304;         // 4,194,304 f32
  float* vc = kn + 4194304;         // 4,194,304 f32
  float* qn = vc + 4194304;         // 2,097,152 f32
  float* gg = qn + 2097152;         // 2,097,152 f32
  float* ba = gg + 2097152;         // 32,768 f32  (pre-transformed: 2*sigmoid)
  float* dka = ba + 32768;          // 16,384 f32  (pre-transformed: decay)
  ushort* xb  = (ushort*)(dka + 16384);       // 4,194,304 bf16
  ushort* wb  = xb + 4194304;                 // 4,194,304 bf16
  ushort* pab = wb + 4194304;                 // 2,097,152 bf16
  float* sc = (float*)(pab + 2097152);        // 131,072 f32 per-token scalar packs

  float* out = (float*)d_out;
  float* fstate = out + (size_t)B_ * L_ * HID_;

  const int M = B_ * L_;            // 2048

  // x -> bf16 once
  cvt_bf16<<<4096, 256, 0, stream>>>(x, xb, 1048576);
  // k: proj -> conv+silu+l2norm
  cvt_bf16<<<4096, 256, 0, stream>>>(Wk, wb, 1048576);
  gemm_bf16<<<dim3(16, 16), 256, 0, stream>>>(xb, wb, pa, M, 2048, HID_);
  conv_silu_norm<1><<<dim3(M, 16), 128, 0, stream>>>(pa, conv_k, kn, 2048, 1.0f);
  // v: proj -> conv+silu
  cvt_bf16<<<4096, 256, 0, stream>>>(Wv, wb, 1048576);
  gemm_bf16<<<dim3(16, 16), 256, 0, stream>>>(xb, wb, pa, M, 2048, HID_);
  conv_silu_norm<0><<<dim3(M, 16), 128, 0, stream>>>(pa, conv_v, vc, 2048, 1.0f);
  // q: proj -> conv+silu+l2norm, scaled by 1/sqrt(DH)
  cvt_bf16<<<2048, 256, 0, stream>>>(Wq, wb, 524288);
  gemm_bf16<<<dim3(8, 16), 256, 0, stream>>>(xb, wb, pa, M, KEY_, HID_);
  conv_silu_norm<1><<<dim3(M, 8), 128, 0, stream>>>(pa, conv_q, qn, KEY_,
                                                    0.08838834764831845f);
  // gate projection
  cvt_bf16<<<2048, 256, 0, stream>>>(Wg, wb, 524288);
  gemm_bf16<<<dim3(8, 16), 256, 0, stream>>>(xb, wb, gg, M, KEY_, HID_);
  // beta / decay projections with fused nonlinearity
  gemm_small<1><<<dim3(M * 16 / 4), 256, 0, stream>>>(x, Wb, ba, M, 16, HID_, nullptr, nullptr);
  gemm_small<2><<<dim3(M * 8 / 4), 256, 0, stream>>>(x, Wa, dka, M, 8, HID_, A_log, dt_bias);
  // per-token scalar precompute (k1.k0, q.k0, q.k1 + gather dk/b0/b1)
  dots_kernel<<<dim3(M * H_ / 4), 256, 0, stream>>>(kn, qn, dka, ba, sc);
  // sequential scan (512 independent single-wave blocks, XCD-grouped, DPP reductions)
  scan_kernel<<<dim3(B_ * H_ * 32), 64, 0, stream>>>(qn, kn, vc, sc, pa, fstate);
  // epilogue: gated RMSNorm (bf16 out) then output projection
  rmsnorm_gate<<<dim3(M * H_), 128, 0, stream>>>(pa, gg, o_norm_w, pab);
  cvt_bf16<<<2048, 256, 0, stream>>>(Wo, wb, 524288);
  gemm_bf16<<<dim3(16, 16), 256, 0, stream>>>(pab, wb, out, M, HID_, KEY_);
}